// Round 8
// baseline (240.392 us; speedup 1.0000x reference)
//
#include <hip/hip_runtime.h>

#define B_TOTAL 1024
#define NGRID   294912
#define NTILES  (NGRID / 16)          // 18432 n-tiles
#define MARGIN  6e-4f                 // > 2x the split-bf16 error bound (~1.2e-4)
#define CAP     (1u << 20)            // candidate buffer entries

// ---- ws layout (bytes) ----
#define KEYS_OFF   0u                 // u64 x 1024
#define WSMAX_OFF  8192u              // u32 x 1024 (orderable-uint approx max)
#define CNT_OFF    12288u             // u32 counter
#define CAND_OFF   16384u             // u32 x CAP
#define APACK_OFF  4210688u           // ushort x 1024*32
#define GPACK_OFF  4276224u           // ushort x NGRID*32
#define WS_NEED    23150592u

typedef __attribute__((ext_vector_type(8))) short short8v;
typedef __attribute__((ext_vector_type(4))) float float4v;

__device__ __forceinline__ unsigned short f2bf(float x) {
    unsigned u = __float_as_uint(x);
    unsigned r = ((u >> 16) & 1u) + 0x7FFFu;     // RNE
    return (unsigned short)((u + r) >> 16);
}
__device__ __forceinline__ float bf2f(unsigned short b) {
    return __uint_as_float(((unsigned)b) << 16);
}
__device__ __forceinline__ unsigned ford(float f) {   // order-preserving f32->u32
    unsigned u = __float_as_uint(f);
    return (u & 0x80000000u) ? ~u : (u | 0x80000000u);
}
__device__ __forceinline__ float funord(unsigned u) {
    return __uint_as_float((u & 0x80000000u) ? (u & 0x7FFFFFFFu) : ~u);
}

// ---------------- init ----------------
__global__ __launch_bounds__(256)
void so3_init_kernel(unsigned long long* __restrict__ keys,
                     unsigned* __restrict__ wsmax, unsigned* __restrict__ cnt) {
    int i = blockIdx.x * 256 + threadIdx.x;
    if (i < B_TOTAL) { keys[i] = 0ull; wsmax[i] = 0u; }
    if (i == 0) *cnt = 0u;
}

// ---------------- pack: split-bf16, K=32 slots ----------------
// A slots: [0..8]=hi [9..17]=hi [18..26]=lo [27..31]=0
// G slots: [0..8]=hi [9..17]=lo [18..26]=hi [27..31]=0
// sum over k of Aslot*Gslot = hi*hi + hi*lo + lo*hi  (exact minus lo*lo)
__global__ __launch_bounds__(256)
void so3_pack_kernel(const float* __restrict__ src, unsigned* __restrict__ dst,
                     int nrows, int isA) {
    int id = blockIdx.x * 256 + threadIdx.x;      // one dword (2 slots)
    if (id >= nrows * 16) return;
    int r = id >> 4, i = id & 15;
    unsigned w = 0;
    #pragma unroll
    for (int h = 0; h < 2; ++h) {
        int s = i * 2 + h;
        unsigned short v = 0;
        if (s < 27) {
            int k = (s < 9) ? s : (s < 18 ? s - 9 : s - 18);
            float x = src[(size_t)r * 9 + k];
            unsigned short hi = f2bf(x);
            int wantLo = isA ? (s >= 18) : (s >= 9 && s < 18);
            v = wantLo ? f2bf(x - bf2f(hi)) : hi;
        }
        w |= ((unsigned)v) << (16 * h);
    }
    dst[id] = w;   // coalesced: consecutive threads -> consecutive dwords
}

// ---- shared staging: A_packed -> LDS, XOR-swizzled (2-way conflicts) ----
__device__ __forceinline__ void stage_A(const unsigned short* __restrict__ Ap,
                                        unsigned short* sB, int t) {
    #pragma unroll
    for (int i = 0; i < 16; ++i) {
        int id = t + i * 256;                    // 4096 16B-chunks
        int row = id >> 2, kb = id & 3;
        uint4 v = *(const uint4*)(Ap + row * 32 + kb * 8);
        int skb = kb ^ ((row >> 1) & 3);
        *(uint4*)((char*)sB + row * 64 + skb * 16) = v;
    }
}

// ---------------- pass 1: approx max per query (no index) ----------------
// MFMA roles: A-operand = G-tile (M=16 grid rows), B-operand = A_packed^T
// (N=16 queries). C: col=lane&15 = query, row=(lane>>4)*4+reg = grid row.
__global__ __launch_bounds__(256, 2)
void so3_mfma_max_kernel(const unsigned short* __restrict__ Ap,
                         const unsigned short* __restrict__ Gp,
                         unsigned* __restrict__ wsmax) {
    __shared__ __align__(16) unsigned short sB[1024 * 32];   // 64 KB
    const int t = threadIdx.x;
    stage_A(Ap, sB, t);
    __syncthreads();

    const int l = t & 63, w = t >> 6;
    const int lr = l & 15, lk = l >> 4;
    const int ntile0 = blockIdx.x * 36 + w * 9;   // 9 n-tiles per wave

    float mx[64];
    #pragma unroll
    for (int bt = 0; bt < 64; ++bt) mx[bt] = -1e30f;

    for (int g = 0; g < 3; ++g) {
        short8v af[3];
        #pragma unroll
        for (int d = 0; d < 3; ++d) {
            int nt = ntile0 + g * 3 + d;
            af[d] = *(const short8v*)(Gp + (size_t)(nt * 16 + lr) * 32 + lk * 8);
        }
        #pragma unroll
        for (int bt = 0; bt < 64; ++bt) {
            int row = bt * 16 + lr;
            int skb = lk ^ ((row >> 1) & 3);
            short8v bf = *(const short8v*)((const char*)sB + row * 64 + skb * 16);
            #pragma unroll
            for (int d = 0; d < 3; ++d) {
                float4v c = {0.f, 0.f, 0.f, 0.f};
                c = __builtin_amdgcn_mfma_f32_16x16x32_bf16(af[d], bf, c, 0, 0, 0);
                mx[bt] = fmaxf(mx[bt],
                               fmaxf(fmaxf(c[0], c[1]), fmaxf(c[2], c[3])));
            }
        }
    }
    #pragma unroll
    for (int bt = 0; bt < 64; ++bt) {
        float m = mx[bt];
        m = fmaxf(m, __shfl_xor(m, 16));
        m = fmaxf(m, __shfl_xor(m, 32));
        if (l < 16) {
            unsigned u = ford(m);
            unsigned* p = wsmax + bt * 16 + l;
            if (u > *p) atomicMax(p, u);   // monotone: stale read only over-admits
        }
    }
}

// ---------------- pass 2: emit candidates >= max - MARGIN ----------------
__global__ __launch_bounds__(256, 2)
void so3_mfma_cand_kernel(const unsigned short* __restrict__ Ap,
                          const unsigned short* __restrict__ Gp,
                          const unsigned* __restrict__ wsmax,
                          unsigned* __restrict__ cnt,
                          unsigned* __restrict__ cands) {
    __shared__ __align__(16) unsigned short sB[1024 * 32];
    const int t = threadIdx.x;
    stage_A(Ap, sB, t);

    const int l = t & 63, w = t >> 6;
    const int lr = l & 15, lk = l >> 4;
    const int ntile0 = blockIdx.x * 36 + w * 9;

    float thr[64];
    #pragma unroll
    for (int bt = 0; bt < 64; ++bt)
        thr[bt] = funord(wsmax[bt * 16 + lr]) - MARGIN;
    __syncthreads();

    for (int g = 0; g < 3; ++g) {
        short8v af[3];
        #pragma unroll
        for (int d = 0; d < 3; ++d) {
            int nt = ntile0 + g * 3 + d;
            af[d] = *(const short8v*)(Gp + (size_t)(nt * 16 + lr) * 32 + lk * 8);
        }
        #pragma unroll
        for (int bt = 0; bt < 64; ++bt) {
            int row = bt * 16 + lr;
            int skb = lk ^ ((row >> 1) & 3);
            short8v bf = *(const short8v*)((const char*)sB + row * 64 + skb * 16);
            #pragma unroll
            for (int d = 0; d < 3; ++d) {
                float4v c = {0.f, 0.f, 0.f, 0.f};
                c = __builtin_amdgcn_mfma_f32_16x16x32_bf16(af[d], bf, c, 0, 0, 0);
                float m4 = fmaxf(fmaxf(c[0], c[1]), fmaxf(c[2], c[3]));
                if (__any(m4 >= thr[bt])) {            // rare slow path
                    int nt = ntile0 + g * 3 + d;
                    int b = bt * 16 + lr;
                    #pragma unroll
                    for (int r = 0; r < 4; ++r) {
                        if (c[r] >= thr[bt]) {
                            int n = nt * 16 + lk * 4 + r;
                            unsigned idx = atomicAdd(cnt, 1u);
                            if (idx < CAP)
                                cands[idx] = ((unsigned)b << 19) | (unsigned)n;
                        }
                    }
                }
            }
        }
    }
}

// ---------------- pass 3: exact fp32 rescore of candidates ----------------
__global__ __launch_bounds__(256)
void so3_rescore_kernel(const float* __restrict__ A, const float* __restrict__ G,
                        const unsigned* __restrict__ cnt,
                        const unsigned* __restrict__ cands,
                        unsigned long long* __restrict__ keys) {
    unsigned total = *cnt;
    if (total > CAP) total = CAP;
    const unsigned stride = gridDim.x * 256;
    for (unsigned i = blockIdx.x * 256 + threadIdx.x; i < total; i += stride) {
        unsigned cd = cands[i];
        int b = (int)(cd >> 19), n = (int)(cd & 0x7FFFFu);
        const float* a = A + (size_t)b * 9;
        const float* g = G + (size_t)n * 9;
        // EXACT chain — same order as reference-matching rounds 2..7
        float d;
        d = a[0] * g[0];
        d = fmaf(a[1], g[1], d);
        d = fmaf(a[2], g[2], d);
        d = fmaf(a[3], g[3], d);
        d = fmaf(a[4], g[4], d);
        d = fmaf(a[5], g[5], d);
        d = fmaf(a[6], g[6], d);
        d = fmaf(a[7], g[7], d);
        d = fmaf(a[8], g[8], d);
        unsigned long long key =
            ((unsigned long long)ford(d) << 32) | (unsigned)(~n);
        unsigned long long seen = keys[b];
        if (key > seen) atomicMax(&keys[b], key);
    }
}

// ---------------- final: unpack + gather ----------------
__global__ __launch_bounds__(256)
void so3_final_kernel(const float* __restrict__ G,
                      const unsigned long long* __restrict__ keys,
                      float* __restrict__ out) {
    int b = blockIdx.x * 256 + threadIdx.x;
    if (b >= B_TOTAL) return;
    unsigned long long key = keys[b];
    unsigned hi = (unsigned)(key >> 32);
    int idx = (int)(~(unsigned)key);
    out[b] = funord(hi);
    const float* g = G + (size_t)idx * 9;
    float* o = out + B_TOTAL + (size_t)b * 9;
    #pragma unroll
    for (int k = 0; k < 9; ++k) o[k] = g[k];
}

// ---------------- fallback (round-5 VALU path, 85.9 us known-good) ----------
#define FB_NBLK  2048
#define FB_CHUNK (NGRID / FB_NBLK)
#define FB_NTHR  128
#define FB_BPT   8
__global__ __launch_bounds__(FB_NTHR, 4)
void so3_fb_partial_kernel(const float* __restrict__ A, const float* __restrict__ G,
                           unsigned long long* __restrict__ ws) {
    __shared__ __align__(16) float sG[FB_CHUNK * 12];
    const int t = threadIdx.x;
    const int n0 = blockIdx.x * FB_CHUNK;
    for (int i = t; i < FB_CHUNK * 9; i += FB_NTHR) {
        int row = i / 9, k = i - row * 9;
        sG[row * 12 + k] = G[(size_t)n0 * 9 + i];
    }
    float a[FB_BPT][9];
    #pragma unroll
    for (int j = 0; j < FB_BPT; ++j) {
        const float* ap = A + (size_t)(j * FB_NTHR + t) * 9;
        #pragma unroll
        for (int k = 0; k < 9; ++k) a[j][k] = ap[k];
    }
    float best[FB_BPT]; int bidx[FB_BPT];
    #pragma unroll
    for (int j = 0; j < FB_BPT; ++j) { best[j] = -1e30f; bidx[j] = 0; }
    __syncthreads();
    #pragma unroll 2
    for (int n = 0; n < FB_CHUNK; ++n) {
        const float4* gv = (const float4*)(sG + n * 12);
        const float4 gA = gv[0], gB = gv[1];
        const float g8 = sG[n * 12 + 8];
        const int vn = n0 + n;
        #pragma unroll
        for (int j = 0; j < FB_BPT; ++j) {
            float d;
            d = a[j][0] * gA.x; d = fmaf(a[j][1], gA.y, d); d = fmaf(a[j][2], gA.z, d);
            d = fmaf(a[j][3], gA.w, d); d = fmaf(a[j][4], gB.x, d); d = fmaf(a[j][5], gB.y, d);
            d = fmaf(a[j][6], gB.z, d); d = fmaf(a[j][7], gB.w, d); d = fmaf(a[j][8], g8, d);
            if (d > best[j]) { best[j] = d; bidx[j] = vn; }
        }
    }
    #pragma unroll
    for (int j = 0; j < FB_BPT; ++j) {
        unsigned long long key =
            ((unsigned long long)ford(best[j]) << 32) | (unsigned)(~bidx[j]);
        unsigned long long seen = ws[j * FB_NTHR + t];
        if (key > seen) atomicMax(&ws[j * FB_NTHR + t], key);
    }
}

extern "C" void kernel_launch(void* const* d_in, const int* in_sizes, int n_in,
                              void* d_out, int out_size, void* d_ws, size_t ws_size,
                              hipStream_t stream) {
    const float* A = (const float*)d_in[0];   // rotMat [1024,3,3] fp32
    const float* G = (const float*)d_in[1];   // output_rotmats [294912,3,3] fp32
    float* out = (float*)d_out;
    char* ws = (char*)d_ws;
    unsigned long long* keys = (unsigned long long*)(ws + KEYS_OFF);
    unsigned* wsmax = (unsigned*)(ws + WSMAX_OFF);
    unsigned* cnt   = (unsigned*)(ws + CNT_OFF);
    unsigned* cands = (unsigned*)(ws + CAND_OFF);
    unsigned short* Ap = (unsigned short*)(ws + APACK_OFF);
    unsigned short* Gp = (unsigned short*)(ws + GPACK_OFF);

    if (ws_size < WS_NEED) {   // defensive: unknown ws budget -> proven VALU path
        hipLaunchKernelGGL(so3_init_kernel, dim3(4), dim3(256), 0, stream,
                           keys, wsmax, cnt);
        hipLaunchKernelGGL(so3_fb_partial_kernel, dim3(FB_NBLK), dim3(FB_NTHR),
                           0, stream, A, G, keys);
        hipLaunchKernelGGL(so3_final_kernel, dim3(4), dim3(256), 0, stream,
                           G, keys, out);
        return;
    }

    hipLaunchKernelGGL(so3_init_kernel, dim3(4), dim3(256), 0, stream,
                       keys, wsmax, cnt);
    hipLaunchKernelGGL(so3_pack_kernel, dim3((B_TOTAL * 16) / 256), dim3(256),
                       0, stream, A, (unsigned*)Ap, B_TOTAL, 1);
    hipLaunchKernelGGL(so3_pack_kernel, dim3((NGRID * 16) / 256), dim3(256),
                       0, stream, G, (unsigned*)Gp, NGRID, 0);
    hipLaunchKernelGGL(so3_mfma_max_kernel, dim3(512), dim3(256), 0, stream,
                       Ap, Gp, wsmax);
    hipLaunchKernelGGL(so3_mfma_cand_kernel, dim3(512), dim3(256), 0, stream,
                       Ap, Gp, wsmax, cnt, cands);
    hipLaunchKernelGGL(so3_rescore_kernel, dim3(64), dim3(256), 0, stream,
                       A, G, cnt, cands, keys);
    hipLaunchKernelGGL(so3_final_kernel, dim3(4), dim3(256), 0, stream,
                       G, keys, out);
}

// Round 9
// 137.800 us; speedup vs baseline: 1.7445x; 1.7445x over previous
//
#include <hip/hip_runtime.h>

#define B_TOTAL 1024
#define NGRID   294912
#define NTILES  (NGRID / 16)          // 18432 n-tiles
#define MARGIN  6e-4f                 // > 2x split-bf16 error bound (~1.2e-4)
#define CAP     (1u << 20)            // candidate buffer entries

#define QG      8                     // query groups (128 queries each)
#define QT      8                     // 16-query MFMA tiles per group
#define GS      128                   // grid slices
#define TPS     (NTILES / GS)         // 144 tiles per slice
#define TPW     (TPS / 4)             // 36 tiles per wave

// ---- ws layout (bytes) ----
#define KEYS_OFF   0u                 // u64 x 1024
#define WSMAX_OFF  8192u              // u32 x 1024 (orderable-uint approx max)
#define CNT_OFF    12288u             // u32 counter
#define CAND_OFF   16384u             // u32 x CAP
#define APACK_OFF  4210688u           // ushort x 1024*32
#define GPACK_OFF  4276224u           // ushort x NGRID*32
#define WS_NEED    23150592u

typedef __attribute__((ext_vector_type(8))) short short8v;
typedef __attribute__((ext_vector_type(4))) float float4v;

__device__ __forceinline__ unsigned short f2bf(float x) {
    unsigned u = __float_as_uint(x);
    unsigned r = ((u >> 16) & 1u) + 0x7FFFu;     // RNE
    return (unsigned short)((u + r) >> 16);
}
__device__ __forceinline__ float bf2f(unsigned short b) {
    return __uint_as_float(((unsigned)b) << 16);
}
__device__ __forceinline__ unsigned ford(float f) {   // order-preserving f32->u32
    unsigned u = __float_as_uint(f);
    return (u & 0x80000000u) ? ~u : (u | 0x80000000u);
}
__device__ __forceinline__ float funord(unsigned u) {
    return __uint_as_float((u & 0x80000000u) ? (u & 0x7FFFFFFFu) : ~u);
}

// ---------------- init ----------------
__global__ __launch_bounds__(256)
void so3_init_kernel(unsigned long long* __restrict__ keys,
                     unsigned* __restrict__ wsmax, unsigned* __restrict__ cnt) {
    int i = blockIdx.x * 256 + threadIdx.x;
    if (i < B_TOTAL) { keys[i] = 0ull; wsmax[i] = 0u; }
    if (i == 0) *cnt = 0u;
}

// ---------------- pack: split-bf16, K=32 slots (verified round 8) --------
// A slots: [0..8]=hi [9..17]=hi [18..26]=lo [27..31]=0
// G slots: [0..8]=hi [9..17]=lo [18..26]=hi [27..31]=0
// dot over slots = hi*hi + hi*lo + lo*hi  (exact minus lo*lo <= ~3.4e-5)
__global__ __launch_bounds__(256)
void so3_pack_kernel(const float* __restrict__ src, unsigned* __restrict__ dst,
                     int nrows, int isA) {
    int id = blockIdx.x * 256 + threadIdx.x;      // one dword (2 slots)
    if (id >= nrows * 16) return;
    int r = id >> 4, i = id & 15;
    unsigned w = 0;
    #pragma unroll
    for (int h = 0; h < 2; ++h) {
        int s = i * 2 + h;
        unsigned short v = 0;
        if (s < 27) {
            int k = (s < 9) ? s : (s < 18 ? s - 9 : s - 18);
            float x = src[(size_t)r * 9 + k];
            unsigned short hi = f2bf(x);
            int wantLo = isA ? (s >= 18) : (s >= 9 && s < 18);
            v = wantLo ? f2bf(x - bf2f(hi)) : hi;
        }
        w |= ((unsigned)v) << (16 * h);
    }
    dst[id] = w;
}

// ---------------- pass 1: approx max per query ----------------
// Per block: 128 queries (blockIdx.x) x 144 grid tiles (blockIdx.y).
// Per wave: 8 loop-invariant B-frags (queries) in regs, sweep 36 G tiles.
// C layout (verified r8): col=lane&15=query, row=(lane>>4)*4+reg=grid row.
// => all 4 c's of a lane share one query -> mx is ONE register per qt.
__global__ __launch_bounds__(256, 4)
void so3_mfma_max_kernel(const unsigned short* __restrict__ Ap,
                         const unsigned short* __restrict__ Gp,
                         unsigned* __restrict__ wsmax) {
    const int t = threadIdx.x, l = t & 63, w = t >> 6;
    const int lr = l & 15, lk = l >> 4;
    const int qbase = blockIdx.x * 128;
    const int tile0 = blockIdx.y * TPS + w * TPW;

    short8v bf[QT];
    #pragma unroll
    for (int qt = 0; qt < QT; ++qt)
        bf[qt] = *(const short8v*)(Ap + (size_t)(qbase + qt * 16 + lr) * 32 + lk * 8);

    float mx[QT];
    #pragma unroll
    for (int qt = 0; qt < QT; ++qt) mx[qt] = -1e30f;

    short8v af = *(const short8v*)(Gp + (size_t)(tile0 * 16 + lr) * 32 + lk * 8);
    for (int i = 0; i < TPW; ++i) {
        int nx = (i + 1 < TPW) ? (i + 1) : i;          // safe prefetch addr
        short8v afn = *(const short8v*)(Gp + (size_t)((tile0 + nx) * 16 + lr) * 32 + lk * 8);
        #pragma unroll
        for (int qt = 0; qt < QT; ++qt) {
            float4v c = {0.f, 0.f, 0.f, 0.f};
            c = __builtin_amdgcn_mfma_f32_16x16x32_bf16(af, bf[qt], c, 0, 0, 0);
            float m3 = fmaxf(fmaxf(c[0], c[1]), c[2]);          // v_max3
            mx[qt] = fmaxf(fmaxf(m3, c[3]), mx[qt]);            // v_max3
        }
        af = afn;
    }

    #pragma unroll
    for (int qt = 0; qt < QT; ++qt) {
        float m = mx[qt];
        m = fmaxf(m, __shfl_xor(m, 16));
        m = fmaxf(m, __shfl_xor(m, 32));
        if (l < 16) {
            unsigned u = ford(m);
            unsigned* p = wsmax + qbase + qt * 16 + l;
            if (u > *p) atomicMax(p, u);    // monotone: stale read only over-admits
        }
    }
}

// ---------------- pass 2: emit candidates >= max - MARGIN ----------------
__global__ __launch_bounds__(256, 4)
void so3_mfma_cand_kernel(const unsigned short* __restrict__ Ap,
                          const unsigned short* __restrict__ Gp,
                          const unsigned* __restrict__ wsmax,
                          unsigned* __restrict__ cnt,
                          unsigned* __restrict__ cands) {
    const int t = threadIdx.x, l = t & 63, w = t >> 6;
    const int lr = l & 15, lk = l >> 4;
    const int qbase = blockIdx.x * 128;
    const int tile0 = blockIdx.y * TPS + w * TPW;

    short8v bf[QT];
    float thr[QT];
    #pragma unroll
    for (int qt = 0; qt < QT; ++qt) {
        bf[qt] = *(const short8v*)(Ap + (size_t)(qbase + qt * 16 + lr) * 32 + lk * 8);
        thr[qt] = funord(wsmax[qbase + qt * 16 + lr]) - MARGIN;
    }

    short8v af = *(const short8v*)(Gp + (size_t)(tile0 * 16 + lr) * 32 + lk * 8);
    for (int i = 0; i < TPW; ++i) {
        int nx = (i + 1 < TPW) ? (i + 1) : i;
        short8v afn = *(const short8v*)(Gp + (size_t)((tile0 + nx) * 16 + lr) * 32 + lk * 8);
        #pragma unroll
        for (int qt = 0; qt < QT; ++qt) {
            float4v c = {0.f, 0.f, 0.f, 0.f};
            c = __builtin_amdgcn_mfma_f32_16x16x32_bf16(af, bf[qt], c, 0, 0, 0);
            float m3 = fmaxf(fmaxf(c[0], c[1]), c[2]);
            float m4 = fmaxf(m3, c[3]);
            if (m4 >= thr[qt]) {                     // rare slow path (per-lane)
                int nt = tile0 + i;
                int b = qbase + qt * 16 + lr;
                #pragma unroll
                for (int r = 0; r < 4; ++r) {
                    if (c[r] >= thr[qt]) {
                        int n = nt * 16 + lk * 4 + r;
                        unsigned idx = atomicAdd(cnt, 1u);
                        if (idx < CAP)
                            cands[idx] = ((unsigned)b << 19) | (unsigned)n;
                    }
                }
            }
        }
        af = afn;
    }
}

// ---------------- pass 3: exact fp32 rescore of candidates ----------------
__global__ __launch_bounds__(256)
void so3_rescore_kernel(const float* __restrict__ A, const float* __restrict__ G,
                        const unsigned* __restrict__ cnt,
                        const unsigned* __restrict__ cands,
                        unsigned long long* __restrict__ keys) {
    unsigned total = *cnt;
    if (total > CAP) total = CAP;
    const unsigned stride = gridDim.x * 256;
    for (unsigned i = blockIdx.x * 256 + threadIdx.x; i < total; i += stride) {
        unsigned cd = cands[i];
        int b = (int)(cd >> 19), n = (int)(cd & 0x7FFFFu);
        const float* a = A + (size_t)b * 9;
        const float* g = G + (size_t)n * 9;
        // EXACT chain — identical order to reference-matching rounds 2..8
        float d;
        d = a[0] * g[0];
        d = fmaf(a[1], g[1], d);
        d = fmaf(a[2], g[2], d);
        d = fmaf(a[3], g[3], d);
        d = fmaf(a[4], g[4], d);
        d = fmaf(a[5], g[5], d);
        d = fmaf(a[6], g[6], d);
        d = fmaf(a[7], g[7], d);
        d = fmaf(a[8], g[8], d);
        unsigned long long key =
            ((unsigned long long)ford(d) << 32) | (unsigned)(~n);
        unsigned long long seen = keys[b];
        if (key > seen) atomicMax(&keys[b], key);
    }
}

// ---------------- final: unpack + gather ----------------
__global__ __launch_bounds__(256)
void so3_final_kernel(const float* __restrict__ G,
                      const unsigned long long* __restrict__ keys,
                      float* __restrict__ out) {
    int b = blockIdx.x * 256 + threadIdx.x;
    if (b >= B_TOTAL) return;
    unsigned long long key = keys[b];
    unsigned hi = (unsigned)(key >> 32);
    int idx = (int)(~(unsigned)key);
    out[b] = funord(hi);
    const float* g = G + (size_t)idx * 9;
    float* o = out + B_TOTAL + (size_t)b * 9;
    #pragma unroll
    for (int k = 0; k < 9; ++k) o[k] = g[k];
}

// ---------------- fallback (round-5 VALU path, 85.9 us known-good) --------
#define FB_NBLK  2048
#define FB_CHUNK (NGRID / FB_NBLK)
#define FB_NTHR  128
#define FB_BPT   8
__global__ __launch_bounds__(FB_NTHR, 4)
void so3_fb_partial_kernel(const float* __restrict__ A, const float* __restrict__ G,
                           unsigned long long* __restrict__ ws) {
    __shared__ __align__(16) float sG[FB_CHUNK * 12];
    const int t = threadIdx.x;
    const int n0 = blockIdx.x * FB_CHUNK;
    for (int i = t; i < FB_CHUNK * 9; i += FB_NTHR) {
        int row = i / 9, k = i - row * 9;
        sG[row * 12 + k] = G[(size_t)n0 * 9 + i];
    }
    float a[FB_BPT][9];
    #pragma unroll
    for (int j = 0; j < FB_BPT; ++j) {
        const float* ap = A + (size_t)(j * FB_NTHR + t) * 9;
        #pragma unroll
        for (int k = 0; k < 9; ++k) a[j][k] = ap[k];
    }
    float best[FB_BPT]; int bidx[FB_BPT];
    #pragma unroll
    for (int j = 0; j < FB_BPT; ++j) { best[j] = -1e30f; bidx[j] = 0; }
    __syncthreads();
    #pragma unroll 2
    for (int n = 0; n < FB_CHUNK; ++n) {
        const float4* gv = (const float4*)(sG + n * 12);
        const float4 gA = gv[0], gB = gv[1];
        const float g8 = sG[n * 12 + 8];
        const int vn = n0 + n;
        #pragma unroll
        for (int j = 0; j < FB_BPT; ++j) {
            float d;
            d = a[j][0] * gA.x; d = fmaf(a[j][1], gA.y, d); d = fmaf(a[j][2], gA.z, d);
            d = fmaf(a[j][3], gA.w, d); d = fmaf(a[j][4], gB.x, d); d = fmaf(a[j][5], gB.y, d);
            d = fmaf(a[j][6], gB.z, d); d = fmaf(a[j][7], gB.w, d); d = fmaf(a[j][8], g8, d);
            if (d > best[j]) { best[j] = d; bidx[j] = vn; }
        }
    }
    #pragma unroll
    for (int j = 0; j < FB_BPT; ++j) {
        unsigned long long key =
            ((unsigned long long)ford(best[j]) << 32) | (unsigned)(~bidx[j]);
        unsigned long long seen = ws[j * FB_NTHR + t];
        if (key > seen) atomicMax(&ws[j * FB_NTHR + t], key);
    }
}

extern "C" void kernel_launch(void* const* d_in, const int* in_sizes, int n_in,
                              void* d_out, int out_size, void* d_ws, size_t ws_size,
                              hipStream_t stream) {
    const float* A = (const float*)d_in[0];   // rotMat [1024,3,3] fp32
    const float* G = (const float*)d_in[1];   // output_rotmats [294912,3,3] fp32
    float* out = (float*)d_out;
    char* ws = (char*)d_ws;
    unsigned long long* keys = (unsigned long long*)(ws + KEYS_OFF);
    unsigned* wsmax = (unsigned*)(ws + WSMAX_OFF);
    unsigned* cnt   = (unsigned*)(ws + CNT_OFF);
    unsigned* cands = (unsigned*)(ws + CAND_OFF);
    unsigned short* Ap = (unsigned short*)(ws + APACK_OFF);
    unsigned short* Gp = (unsigned short*)(ws + GPACK_OFF);

    if (ws_size < WS_NEED) {   // defensive: unknown ws budget -> proven VALU path
        hipLaunchKernelGGL(so3_init_kernel, dim3(4), dim3(256), 0, stream,
                           keys, wsmax, cnt);
        hipLaunchKernelGGL(so3_fb_partial_kernel, dim3(FB_NBLK), dim3(FB_NTHR),
                           0, stream, A, G, keys);
        hipLaunchKernelGGL(so3_final_kernel, dim3(4), dim3(256), 0, stream,
                           G, keys, out);
        return;
    }

    hipLaunchKernelGGL(so3_init_kernel, dim3(4), dim3(256), 0, stream,
                       keys, wsmax, cnt);
    hipLaunchKernelGGL(so3_pack_kernel, dim3((B_TOTAL * 16) / 256), dim3(256),
                       0, stream, A, (unsigned*)Ap, B_TOTAL, 1);
    hipLaunchKernelGGL(so3_pack_kernel, dim3((NGRID * 16) / 256), dim3(256),
                       0, stream, G, (unsigned*)Gp, NGRID, 0);
    hipLaunchKernelGGL(so3_mfma_max_kernel, dim3(QG, GS), dim3(256), 0, stream,
                       Ap, Gp, wsmax);
    hipLaunchKernelGGL(so3_mfma_cand_kernel, dim3(QG, GS), dim3(256), 0, stream,
                       Ap, Gp, wsmax, cnt, cands);
    hipLaunchKernelGGL(so3_rescore_kernel, dim3(64), dim3(256), 0, stream,
                       A, G, cnt, cands, keys);
    hipLaunchKernelGGL(so3_final_kernel, dim3(4), dim3(256), 0, stream,
                       G, keys, out);
}